// Round 1
// baseline (651.928 us; speedup 1.0000x reference)
//
#include <hip/hip_runtime.h>
#include <stdint.h>

// Problem constants (fixed by reference: scores (4, 131072) f32, m=4096, tau=1)
#define BROWS 4
#define NCOLS 131072           // 2^17
#define MREF  4096
#define HIST_BITS 13
#define NBUCK (1 << HIST_BITS) // 8192
#define USHIFT (32 - HIST_BITS)
#define CAP 8192               // candidate cap per row (top bucket adds ~600)

__device__ __forceinline__ uint32_t orderable(float f) {
    uint32_t u = __float_as_uint(f);
    return (u & 0x80000000u) ? ~u : (u | 0x80000000u);
}
__device__ __forceinline__ float unorderable(uint32_t u) {
    uint32_t b = (u & 0x80000000u) ? (u & 0x7FFFFFFFu) : ~u;
    return __uint_as_float(b);
}

__global__ void k_zero(uint32_t* hist, uint32_t* cnt) {
    int i = blockIdx.x * blockDim.x + threadIdx.x;
    int tot = BROWS * NBUCK;
    for (; i < tot; i += gridDim.x * blockDim.x) hist[i] = 0u;
    if (blockIdx.x == 0 && threadIdx.x < BROWS) cnt[threadIdx.x] = 0u;
}

__global__ void k_hist(const float* __restrict__ sc, uint32_t* __restrict__ hist) {
    int i = blockIdx.x * blockDim.x + threadIdx.x;
    for (; i < BROWS * NCOLS; i += gridDim.x * blockDim.x) {
        int row = i >> 17;
        uint32_t u = orderable(sc[i]);
        atomicAdd(&hist[(row << HIST_BITS) + (u >> USHIFT)], 1u);
    }
}

// One block per row: find highest bucket H s.t. count(bucket >= H) >= MREF
__global__ void k_thresh(const uint32_t* __restrict__ hist, uint32_t* __restrict__ Hrow) {
    __shared__ uint32_t part[256];
    int row = blockIdx.x;
    const uint32_t* h = hist + (row << HIST_BITS);
    const int chunk = NBUCK / 256; // 32 buckets per thread, descending chunks
    uint32_t s = 0;
    int top = NBUCK - 1 - (int)threadIdx.x * chunk;
    for (int k = 0; k < chunk; ++k) s += h[top - k];
    part[threadIdx.x] = s;
    __syncthreads();
    if (threadIdx.x == 0) {
        uint32_t cum = 0; int H = 0;
        for (int t = 0; t < 256; ++t) {
            if (cum + part[t] >= (uint32_t)MREF) {
                int tp = NBUCK - 1 - t * chunk;
                for (int k2 = 0; k2 < chunk; ++k2) {
                    cum += h[tp - k2];
                    if (cum >= (uint32_t)MREF) { H = tp - k2; break; }
                }
                break;
            }
            cum += part[t];
        }
        Hrow[row] = (uint32_t)H;
    }
}

__global__ void k_compact(const float* __restrict__ sc, const uint32_t* __restrict__ Hrow,
                          uint32_t* __restrict__ cnt, uint64_t* __restrict__ cand) {
    int i = blockIdx.x * blockDim.x + threadIdx.x;
    for (; i < BROWS * NCOLS; i += gridDim.x * blockDim.x) {
        int row = i >> 17;
        int col = i & (NCOLS - 1);
        uint32_t u = orderable(sc[i]);
        if ((u >> USHIFT) >= Hrow[row]) {
            uint32_t pos = atomicAdd(&cnt[row], 1u);
            if (pos < CAP)
                cand[(size_t)row * CAP + pos] = ((uint64_t)(~u) << 32) | (uint32_t)col;
        }
    }
}

// One block per row: bitonic sort CAP keys ascending in LDS.
// key = (~u)<<32 | idx  -> ascending key == (value desc, idx asc) == jax top_k order.
__global__ void k_sort(const uint64_t* __restrict__ cand, const uint32_t* __restrict__ cnt,
                       float* __restrict__ rv, uint32_t* __restrict__ ri) {
    __shared__ uint64_t lds[CAP]; // 64 KiB
    int row = blockIdx.x;
    uint32_t c = cnt[row]; if (c > CAP) c = CAP;
    for (int t = threadIdx.x; t < CAP; t += blockDim.x)
        lds[t] = (t < (int)c) ? cand[(size_t)row * CAP + t] : ~0ULL;
    __syncthreads();
    for (int k = 2; k <= CAP; k <<= 1) {
        for (int j = k >> 1; j > 0; j >>= 1) {
            for (int i = threadIdx.x; i < CAP; i += blockDim.x) {
                int ixj = i ^ j;
                if (ixj > i) {
                    uint64_t a = lds[i], b = lds[ixj];
                    bool up = ((i & k) == 0);
                    if ((a > b) == up) { lds[i] = b; lds[ixj] = a; }
                }
            }
            __syncthreads();
        }
    }
    for (int t = threadIdx.x; t < MREF; t += blockDim.x) {
        uint64_t key = lds[t];
        uint32_t u = ~(uint32_t)(key >> 32);
        rv[row * MREF + t] = unorderable(u);
        ri[row * MREF + t] = (uint32_t)(key & 0xFFFFFFFFu);
    }
}

// 512 blocks per row x 256 threads: nearest-ref mapping with float32 tie emulation.
__global__ void k_map(const float* __restrict__ sc, const float* __restrict__ rv,
                      const uint32_t* __restrict__ ri, int* __restrict__ out) {
    __shared__ float srv[MREF]; // 16 KiB
    int row = blockIdx.x >> 9;
    int col = ((blockIdx.x & 511) << 8) + threadIdx.x;
    const float* rvr = rv + row * MREF;
    for (int t = threadIdx.x; t < MREF; t += blockDim.x) srv[t] = rvr[t];
    __syncthreads();

    float s = sc[row * NCOLS + col];
    // first j with srv[j] <= s (srv descending)
    int lo = 0, hi = MREF;
    while (lo < hi) { int mid = (lo + hi) >> 1; if (srv[mid] <= s) hi = mid; else lo = mid + 1; }
    int p = lo, jmin;
    if (p == 0) jmin = 0;
    else if (p == MREF) jmin = MREF - 1;
    else {
        float dp = fabsf(s - srv[p]);
        float dm = fabsf(s - srv[p - 1]);
        jmin = (dm <= dp) ? (p - 1) : p; // tie -> smaller j (argmax-first)
    }
    float pmax = -fabsf(s - srv[jmin]);
    int jans = jmin;
    // exp-level tie merge: exp(pw - pmax) rounds to 1.0f => equal softmax prob,
    // argmax picks the smallest such j. Distances grow monotonically downward,
    // so the winner set is contiguous; scan until it breaks.
    for (int j = jmin - 1; j >= 0; --j) {
        float pw = -fabsf(s - srv[j]);
        if (expf(pw - pmax) == 1.0f) jans = j; else break;
    }
    out[row * NCOLS + col] = (int)ri[row * MREF + jans];
}

extern "C" void kernel_launch(void* const* d_in, const int* in_sizes, int n_in,
                              void* d_out, int out_size, void* d_ws, size_t ws_size,
                              hipStream_t stream) {
    const float* sc = (const float*)d_in[0];
    int* out = (int*)d_out;
    char* w = (char*)d_ws;

    // ws layout (bytes): hist[4*8192 u32]=131072 | Hrow[4 u32] | cnt[4 u32] |
    //                    cand[4*8192 u64]=262144 | rv[4*4096 f32] | ri[4*4096 u32]
    uint32_t* hist = (uint32_t*)w;
    uint32_t* Hrow = (uint32_t*)(w + 131072);
    uint32_t* cnt  = (uint32_t*)(w + 131088);
    uint64_t* cand = (uint64_t*)(w + 131104);
    float*    rv   = (float*)   (w + 131104 + 262144);
    uint32_t* ri   = (uint32_t*)(w + 131104 + 262144 + 65536);

    k_zero   <<<64,   256, 0, stream>>>(hist, cnt);
    k_hist   <<<512,  256, 0, stream>>>(sc, hist);
    k_thresh <<<BROWS,256, 0, stream>>>(hist, Hrow);
    k_compact<<<512,  256, 0, stream>>>(sc, Hrow, cnt, cand);
    k_sort   <<<BROWS,1024,0, stream>>>(cand, cnt, rv, ri);
    k_map    <<<BROWS*512, 256, 0, stream>>>(sc, rv, ri, out);
}

// Round 2
// 313.023 us; speedup vs baseline: 2.0827x; 2.0827x over previous
//
#include <hip/hip_runtime.h>
#include <stdint.h>

// Problem constants (fixed by reference: scores (4, 131072) f32, m=4096, tau=1)
#define BROWS 4
#define NCOLS 131072           // 2^17
#define MREF  4096
#define HIST_BITS 13
#define NBUCK (1 << HIST_BITS) // 8192
#define USHIFT (32 - HIST_BITS)
#define CAP 8192               // candidate cap per row (top bucket adds ~600)
#define CNT_STRIDE 32          // u32s: 128B between row counters (no line sharing)

__device__ __forceinline__ uint32_t orderable(float f) {
    uint32_t u = __float_as_uint(f);
    return (u & 0x80000000u) ? ~u : (u | 0x80000000u);
}
__device__ __forceinline__ float unorderable(uint32_t u) {
    uint32_t b = (u & 0x80000000u) ? (u & 0x7FFFFFFFu) : ~u;
    return __uint_as_float(b);
}

__global__ void k_zero(uint32_t* hist, uint32_t* cnt) {
    int i = blockIdx.x * blockDim.x + threadIdx.x;
    int tot = BROWS * NBUCK;
    for (; i < tot; i += gridDim.x * blockDim.x) hist[i] = 0u;
    if (blockIdx.x == 0 && threadIdx.x < BROWS) cnt[threadIdx.x * CNT_STRIDE] = 0u;
}

__global__ void k_hist(const float* __restrict__ sc, uint32_t* __restrict__ hist) {
    int i = blockIdx.x * blockDim.x + threadIdx.x;
    for (; i < BROWS * NCOLS; i += gridDim.x * blockDim.x) {
        int row = i >> 17;
        uint32_t u = orderable(sc[i]);
        atomicAdd(&hist[(row << HIST_BITS) + (u >> USHIFT)], 1u);
    }
}

// One block per row: find highest bucket H s.t. count(bucket >= H) >= MREF
__global__ void k_thresh(const uint32_t* __restrict__ hist, uint32_t* __restrict__ Hrow) {
    __shared__ uint32_t part[256];
    int row = blockIdx.x;
    const uint32_t* h = hist + (row << HIST_BITS);
    const int chunk = NBUCK / 256; // 32 buckets per thread, descending chunks
    uint32_t s = 0;
    int top = NBUCK - 1 - (int)threadIdx.x * chunk;
    for (int k = 0; k < chunk; ++k) s += h[top - k];
    part[threadIdx.x] = s;
    __syncthreads();
    if (threadIdx.x == 0) {
        uint32_t cum = 0; int H = 0;
        for (int t = 0; t < 256; ++t) {
            if (cum + part[t] >= (uint32_t)MREF) {
                int tp = NBUCK - 1 - t * chunk;
                for (int k2 = 0; k2 < chunk; ++k2) {
                    cum += h[tp - k2];
                    if (cum >= (uint32_t)MREF) { H = tp - k2; break; }
                }
                break;
            }
            cum += part[t];
        }
        Hrow[row] = (uint32_t)H;
    }
}

// Block-aggregated compaction: 512 blocks; block b -> row b>>7, 1024-col chunk.
// One atomicAdd per BLOCK (was: per candidate, all on one cache line).
__global__ void k_compact(const float* __restrict__ sc, const uint32_t* __restrict__ Hrow,
                          uint32_t* __restrict__ cnt, uint64_t* __restrict__ cand) {
    __shared__ uint32_t pref[256];
    __shared__ uint32_t bbase;
    int row = blockIdx.x >> 7;
    int base = (blockIdx.x & 127) << 10;
    uint32_t H = Hrow[row];
    const float* p = sc + row * NCOLS + base;

    uint32_t myu[4]; uint32_t mycol[4]; uint32_t n = 0;
    #pragma unroll
    for (int k = 0; k < 4; ++k) {
        int c = (int)threadIdx.x + (k << 8);
        uint32_t u = orderable(p[c]);
        if ((u >> USHIFT) >= H) { myu[n] = u; mycol[n] = (uint32_t)(base + c); ++n; }
    }
    pref[threadIdx.x] = n;
    __syncthreads();
    // inclusive scan over 256 counts
    for (int off = 1; off < 256; off <<= 1) {
        uint32_t v = (threadIdx.x >= (uint32_t)off) ? pref[threadIdx.x - off] : 0u;
        __syncthreads();
        pref[threadIdx.x] += v;
        __syncthreads();
    }
    if (threadIdx.x == 255) bbase = atomicAdd(&cnt[row * CNT_STRIDE], pref[255]);
    __syncthreads();
    uint32_t my = bbase + pref[threadIdx.x] - n;
    for (uint32_t k = 0; k < n; ++k) {
        uint32_t pos = my + k;
        if (pos < CAP)
            cand[(size_t)row * CAP + pos] = ((uint64_t)(~myu[k]) << 32) | mycol[k];
    }
}

// One block per row: bitonic sort CAP keys ascending in LDS.
// key = (~u)<<32 | idx  -> ascending key == (value desc, idx asc) == jax top_k order.
__global__ void k_sort(const uint64_t* __restrict__ cand, const uint32_t* __restrict__ cnt,
                       float* __restrict__ rv, uint32_t* __restrict__ ri) {
    __shared__ uint64_t lds[CAP]; // 64 KiB
    int row = blockIdx.x;
    uint32_t c = cnt[row * CNT_STRIDE]; if (c > CAP) c = CAP;
    for (int t = threadIdx.x; t < CAP; t += blockDim.x)
        lds[t] = (t < (int)c) ? cand[(size_t)row * CAP + t] : ~0ULL;
    __syncthreads();
    for (int k = 2; k <= CAP; k <<= 1) {
        for (int j = k >> 1; j > 0; j >>= 1) {
            for (int i = threadIdx.x; i < CAP; i += blockDim.x) {
                int ixj = i ^ j;
                if (ixj > i) {
                    uint64_t a = lds[i], b = lds[ixj];
                    bool up = ((i & k) == 0);
                    if ((a > b) == up) { lds[i] = b; lds[ixj] = a; }
                }
            }
            __syncthreads();
        }
    }
    for (int t = threadIdx.x; t < MREF; t += blockDim.x) {
        uint64_t key = lds[t];
        uint32_t u = ~(uint32_t)(key >> 32);
        rv[row * MREF + t] = unorderable(u);
        ri[row * MREF + t] = (uint32_t)(key & 0xFFFFFFFFu);
    }
}

// 512 blocks per row x 256 threads: nearest-ref mapping with float32 tie emulation.
__global__ void k_map(const float* __restrict__ sc, const float* __restrict__ rv,
                      const uint32_t* __restrict__ ri, int* __restrict__ out) {
    __shared__ float srv[MREF]; // 16 KiB
    int row = blockIdx.x >> 9;
    int col = ((blockIdx.x & 511) << 8) + threadIdx.x;
    const float* rvr = rv + row * MREF;
    for (int t = threadIdx.x; t < MREF; t += blockDim.x) srv[t] = rvr[t];
    __syncthreads();

    float s = sc[row * NCOLS + col];
    // first j with srv[j] <= s (srv descending)
    int lo = 0, hi = MREF;
    while (lo < hi) { int mid = (lo + hi) >> 1; if (srv[mid] <= s) hi = mid; else lo = mid + 1; }
    int p = lo, jmin;
    if (p == 0) jmin = 0;
    else if (p == MREF) jmin = MREF - 1;
    else {
        float dp = fabsf(s - srv[p]);
        float dm = fabsf(s - srv[p - 1]);
        jmin = (dm <= dp) ? (p - 1) : p; // tie -> smaller j (argmax-first)
    }
    float pmax = -fabsf(s - srv[jmin]);
    int jans = jmin;
    // exp-level tie merge: exp(pw - pmax) rounds to 1.0f => equal softmax prob,
    // argmax picks the smallest such j. Distances grow monotonically downward,
    // so the winner set is contiguous; scan until it breaks.
    for (int j = jmin - 1; j >= 0; --j) {
        float pw = -fabsf(s - srv[j]);
        if (expf(pw - pmax) == 1.0f) jans = j; else break;
    }
    out[row * NCOLS + col] = (int)ri[row * MREF + jans];
}

extern "C" void kernel_launch(void* const* d_in, const int* in_sizes, int n_in,
                              void* d_out, int out_size, void* d_ws, size_t ws_size,
                              hipStream_t stream) {
    const float* sc = (const float*)d_in[0];
    int* out = (int*)d_out;
    char* w = (char*)d_ws;

    // ws layout (bytes): hist[4*8192 u32]=131072 | Hrow[4 u32]=16 | pad |
    //                    cnt[4*CNT_STRIDE u32]=512 | cand[4*8192 u64]=262144 |
    //                    rv[4*4096 f32]=65536 | ri[4*4096 u32]=65536
    uint32_t* hist = (uint32_t*)w;
    uint32_t* Hrow = (uint32_t*)(w + 131072);
    uint32_t* cnt  = (uint32_t*)(w + 131072 + 128);
    uint64_t* cand = (uint64_t*)(w + 131072 + 128 + 512);
    float*    rv   = (float*)   (w + 131072 + 128 + 512 + 262144);
    uint32_t* ri   = (uint32_t*)(w + 131072 + 128 + 512 + 262144 + 65536);

    k_zero   <<<64,   256, 0, stream>>>(hist, cnt);
    k_hist   <<<512,  256, 0, stream>>>(sc, hist);
    k_thresh <<<BROWS,256, 0, stream>>>(hist, Hrow);
    k_compact<<<512,  256, 0, stream>>>(sc, Hrow, cnt, cand);
    k_sort   <<<BROWS,1024,0, stream>>>(cand, cnt, rv, ri);
    k_map    <<<BROWS*512, 256, 0, stream>>>(sc, rv, ri, out);
}

// Round 3
// 149.515 us; speedup vs baseline: 4.3603x; 2.0936x over previous
//
#include <hip/hip_runtime.h>
#include <stdint.h>

// Problem constants (fixed by reference: scores (4, 131072) f32, m=4096, tau=1)
#define BROWS 4
#define NCOLS 131072           // 2^17
#define MREF  4096
#define HIST_BITS 13
#define NBUCK (1 << HIST_BITS) // 8192
#define USHIFT (32 - HIST_BITS)
#define CAP 8192               // candidate cap per row (top bucket adds ~1300 max)
#define CNT_STRIDE 32          // u32s: 128B between row counters (no line sharing)
#define HIST_BLK_PER_ROW 8     // blocks per row in k_hist

__device__ __forceinline__ uint32_t orderable(float f) {
    uint32_t u = __float_as_uint(f);
    return (u & 0x80000000u) ? ~u : (u | 0x80000000u);
}
__device__ __forceinline__ float unorderable(uint32_t u) {
    uint32_t b = (u & 0x80000000u) ? (u & 0x7FFFFFFFu) : ~u;
    return __uint_as_float(b);
}

__global__ void k_zero(uint32_t* hist, uint32_t* cnt) {
    int i = blockIdx.x * blockDim.x + threadIdx.x;
    int tot = BROWS * NBUCK;
    for (; i < tot; i += gridDim.x * blockDim.x) hist[i] = 0u;
    if (blockIdx.x == 0 && threadIdx.x < BROWS) cnt[threadIdx.x * CNT_STRIDE] = 0u;
}

// LDS-privatized histogram: 8 blocks/row, each builds a full LDS hist of its
// 16384-element chunk, then flushes only nonzero buckets (max 8-way global
// same-address contention instead of ~1200-way).
__global__ void k_hist(const float* __restrict__ sc, uint32_t* __restrict__ hist) {
    __shared__ uint32_t h[NBUCK]; // 32 KiB
    for (int t = threadIdx.x; t < NBUCK; t += blockDim.x) h[t] = 0u;
    __syncthreads();
    int row  = blockIdx.x / HIST_BLK_PER_ROW;
    int part = blockIdx.x % HIST_BLK_PER_ROW;
    const int CHUNK = NCOLS / HIST_BLK_PER_ROW; // 16384
    const float* p = sc + row * NCOLS + part * CHUNK;
    for (int c = threadIdx.x; c < CHUNK; c += blockDim.x) {
        uint32_t u = orderable(p[c]);
        atomicAdd(&h[u >> USHIFT], 1u);
    }
    __syncthreads();
    uint32_t* g = hist + (row << HIST_BITS);
    for (int t = threadIdx.x; t < NBUCK; t += blockDim.x) {
        uint32_t v = h[t];
        if (v) atomicAdd(&g[t], v);
    }
}

// One block per row: find highest bucket H s.t. count(bucket >= H) >= MREF
__global__ void k_thresh(const uint32_t* __restrict__ hist, uint32_t* __restrict__ Hrow) {
    __shared__ uint32_t part[256];
    int row = blockIdx.x;
    const uint32_t* h = hist + (row << HIST_BITS);
    const int chunk = NBUCK / 256; // 32 buckets per thread, descending chunks
    uint32_t s = 0;
    int top = NBUCK - 1 - (int)threadIdx.x * chunk;
    for (int k = 0; k < chunk; ++k) s += h[top - k];
    part[threadIdx.x] = s;
    __syncthreads();
    if (threadIdx.x == 0) {
        uint32_t cum = 0; int H = 0;
        for (int t = 0; t < 256; ++t) {
            if (cum + part[t] >= (uint32_t)MREF) {
                int tp = NBUCK - 1 - t * chunk;
                for (int k2 = 0; k2 < chunk; ++k2) {
                    cum += h[tp - k2];
                    if (cum >= (uint32_t)MREF) { H = tp - k2; break; }
                }
                break;
            }
            cum += part[t];
        }
        Hrow[row] = (uint32_t)H;
    }
}

// Block-aggregated compaction: 512 blocks; block b -> row b>>7, 1024-col chunk.
// One atomicAdd per BLOCK.
__global__ void k_compact(const float* __restrict__ sc, const uint32_t* __restrict__ Hrow,
                          uint32_t* __restrict__ cnt, uint64_t* __restrict__ cand) {
    __shared__ uint32_t pref[256];
    __shared__ uint32_t bbase;
    int row = blockIdx.x >> 7;
    int base = (blockIdx.x & 127) << 10;
    uint32_t H = Hrow[row];
    const float* p = sc + row * NCOLS + base;

    uint32_t myu[4]; uint32_t mycol[4]; uint32_t n = 0;
    #pragma unroll
    for (int k = 0; k < 4; ++k) {
        int c = (int)threadIdx.x + (k << 8);
        uint32_t u = orderable(p[c]);
        if ((u >> USHIFT) >= H) { myu[n] = u; mycol[n] = (uint32_t)(base + c); ++n; }
    }
    pref[threadIdx.x] = n;
    __syncthreads();
    // inclusive scan over 256 counts
    for (int off = 1; off < 256; off <<= 1) {
        uint32_t v = (threadIdx.x >= (uint32_t)off) ? pref[threadIdx.x - off] : 0u;
        __syncthreads();
        pref[threadIdx.x] += v;
        __syncthreads();
    }
    if (threadIdx.x == 255) bbase = atomicAdd(&cnt[row * CNT_STRIDE], pref[255]);
    __syncthreads();
    uint32_t my = bbase + pref[threadIdx.x] - n;
    for (uint32_t k = 0; k < n; ++k) {
        uint32_t pos = my + k;
        if (pos < CAP)
            cand[(size_t)row * CAP + pos] = ((uint64_t)(~myu[k]) << 32) | mycol[k];
    }
}

// One block per row: bitonic sort CAP keys ascending in LDS.
// key = (~u)<<32 | idx  -> ascending key == (value desc, idx asc) == jax top_k order.
__global__ void k_sort(const uint64_t* __restrict__ cand, const uint32_t* __restrict__ cnt,
                       float* __restrict__ rv, uint32_t* __restrict__ ri) {
    __shared__ uint64_t lds[CAP]; // 64 KiB
    int row = blockIdx.x;
    uint32_t c = cnt[row * CNT_STRIDE]; if (c > CAP) c = CAP;
    for (int t = threadIdx.x; t < CAP; t += blockDim.x)
        lds[t] = (t < (int)c) ? cand[(size_t)row * CAP + t] : ~0ULL;
    __syncthreads();
    for (int k = 2; k <= CAP; k <<= 1) {
        for (int j = k >> 1; j > 0; j >>= 1) {
            for (int i = threadIdx.x; i < CAP; i += blockDim.x) {
                int ixj = i ^ j;
                if (ixj > i) {
                    uint64_t a = lds[i], b = lds[ixj];
                    bool up = ((i & k) == 0);
                    if ((a > b) == up) { lds[i] = b; lds[ixj] = a; }
                }
            }
            __syncthreads();
        }
    }
    for (int t = threadIdx.x; t < MREF; t += blockDim.x) {
        uint64_t key = lds[t];
        uint32_t u = ~(uint32_t)(key >> 32);
        rv[row * MREF + t] = unorderable(u);
        ri[row * MREF + t] = (uint32_t)(key & 0xFFFFFFFFu);
    }
}

// 512 blocks per row x 256 threads: nearest-ref mapping with float32 tie emulation.
__global__ void k_map(const float* __restrict__ sc, const float* __restrict__ rv,
                      const uint32_t* __restrict__ ri, int* __restrict__ out) {
    __shared__ float srv[MREF]; // 16 KiB
    int row = blockIdx.x >> 9;
    int col = ((blockIdx.x & 511) << 8) + threadIdx.x;
    const float* rvr = rv + row * MREF;
    for (int t = threadIdx.x; t < MREF; t += blockDim.x) srv[t] = rvr[t];
    __syncthreads();

    float s = sc[row * NCOLS + col];
    // first j with srv[j] <= s (srv descending)
    int lo = 0, hi = MREF;
    while (lo < hi) { int mid = (lo + hi) >> 1; if (srv[mid] <= s) hi = mid; else lo = mid + 1; }
    int p = lo, jmin;
    if (p == 0) jmin = 0;
    else if (p == MREF) jmin = MREF - 1;
    else {
        float dp = fabsf(s - srv[p]);
        float dm = fabsf(s - srv[p - 1]);
        jmin = (dm <= dp) ? (p - 1) : p; // tie -> smaller j (argmax-first)
    }
    float pmax = -fabsf(s - srv[jmin]);
    int jans = jmin;
    // exp-level tie merge: exp(pw - pmax) rounds to 1.0f => equal softmax prob,
    // argmax picks the smallest such j. Distances grow monotonically downward,
    // so the winner set is contiguous; scan until it breaks.
    for (int j = jmin - 1; j >= 0; --j) {
        float pw = -fabsf(s - srv[j]);
        if (expf(pw - pmax) == 1.0f) jans = j; else break;
    }
    out[row * NCOLS + col] = (int)ri[row * MREF + jans];
}

extern "C" void kernel_launch(void* const* d_in, const int* in_sizes, int n_in,
                              void* d_out, int out_size, void* d_ws, size_t ws_size,
                              hipStream_t stream) {
    const float* sc = (const float*)d_in[0];
    int* out = (int*)d_out;
    char* w = (char*)d_ws;

    // ws layout (bytes): hist[4*8192 u32]=131072 | Hrow[4 u32]=16 | pad |
    //                    cnt[4*CNT_STRIDE u32]=512 | cand[4*8192 u64]=262144 |
    //                    rv[4*4096 f32]=65536 | ri[4*4096 u32]=65536
    uint32_t* hist = (uint32_t*)w;
    uint32_t* Hrow = (uint32_t*)(w + 131072);
    uint32_t* cnt  = (uint32_t*)(w + 131072 + 128);
    uint64_t* cand = (uint64_t*)(w + 131072 + 128 + 512);
    float*    rv   = (float*)   (w + 131072 + 128 + 512 + 262144);
    uint32_t* ri   = (uint32_t*)(w + 131072 + 128 + 512 + 262144 + 65536);

    k_zero   <<<64,   256, 0, stream>>>(hist, cnt);
    k_hist   <<<BROWS * HIST_BLK_PER_ROW, 256, 0, stream>>>(sc, hist);
    k_thresh <<<BROWS,256, 0, stream>>>(hist, Hrow);
    k_compact<<<512,  256, 0, stream>>>(sc, Hrow, cnt, cand);
    k_sort   <<<BROWS,1024,0, stream>>>(cand, cnt, rv, ri);
    k_map    <<<BROWS*512, 256, 0, stream>>>(sc, rv, ri, out);
}

// Round 7
// 86.428 us; speedup vs baseline: 7.5430x; 1.7299x over previous
//
#include <hip/hip_runtime.h>
#include <stdint.h>

// Problem constants (fixed by reference: scores (4, 131072) f32, m=4096, tau=1)
#define BROWS 4
#define NCOLS 131072           // 2^17
#define MREF  4096
#define HIST_BITS 13
#define NBUCK (1 << HIST_BITS) // 8192
#define USHIFT (32 - HIST_BITS)
#define CAP 6144               // candidates per row (<= 4095 + threshold-bucket count)
#define HIST_BLK_PER_ROW 8
#define NPART 8
#define PQUOTA 768             // CAP / NPART
#define PARTCAP 2048           // fixed bitonic size; max partition = 768 + ~700 bucket

__device__ __forceinline__ uint32_t orderable(float f) {
    uint32_t u = __float_as_uint(f);
    return (u & 0x80000000u) ? ~u : (u | 0x80000000u);
}
__device__ __forceinline__ float unorderable(uint32_t u) {
    uint32_t b = (u & 0x80000000u) ? (u & 0x7FFFFFFFu) : ~u;
    return __uint_as_float(b);
}

__global__ void k_zero(uint32_t* hist) {
    int i = blockIdx.x * blockDim.x + threadIdx.x;
    int tot = BROWS * NBUCK;
    for (; i < tot; i += gridDim.x * blockDim.x) hist[i] = 0u;
}

// LDS-privatized histogram: 8 blocks/row over 16384-element chunks. (round-3 exact)
__global__ void k_hist(const float* __restrict__ sc, uint32_t* __restrict__ hist) {
    __shared__ uint32_t h[NBUCK]; // 32 KiB
    for (int t = threadIdx.x; t < NBUCK; t += blockDim.x) h[t] = 0u;
    __syncthreads();
    int row  = blockIdx.x / HIST_BLK_PER_ROW;
    int part = blockIdx.x % HIST_BLK_PER_ROW;
    const int CHUNK = NCOLS / HIST_BLK_PER_ROW; // 16384
    const float* p = sc + row * NCOLS + part * CHUNK;
    for (int c = threadIdx.x; c < CHUNK; c += blockDim.x) {
        uint32_t u = orderable(p[c]);
        atomicAdd(&h[u >> USHIFT], 1u);
    }
    __syncthreads();
    uint32_t* g = hist + (row << HIST_BITS);
    for (int t = threadIdx.x; t < NBUCK; t += blockDim.x) {
        uint32_t v = h[t];
        if (v) atomicAdd(&g[t], v);
    }
}

// One block per row: round-3 structure (part[] presums + thread-0 serial walk).
// The walk additionally records NPART-1 quota-crossing boundaries B[p] and
// partition start offsets. Partition p = buckets b with B[p+1] < b <= B[p];
// start[p] = #elements in buckets > B[p]. Unset boundaries -> H-1 (empty tail).
__global__ void k_thresh(const uint32_t* __restrict__ hist, uint32_t* __restrict__ Hrow,
                         int* __restrict__ Bs, uint32_t* __restrict__ pcur,
                         uint32_t* __restrict__ pse) {
    __shared__ uint32_t part[256];
    int row = blockIdx.x;
    const uint32_t* h = hist + (row << HIST_BITS);
    int bhi = NBUCK - 1 - (int)threadIdx.x * 32;
    uint32_t run = 0;
    for (int k = 0; k < 32; ++k) run += h[bhi - k];
    part[threadIdx.x] = run;
    __syncthreads();
    if (threadIdx.x == 0) {
        int   Bloc[NPART];
        uint32_t Ploc[NPART];
        for (int p = 0; p < NPART; ++p) { Bloc[p] = -1; Ploc[p] = 0u; }
        uint32_t cum = 0, T = 0;
        int H = 0, pi = 1;
        bool done = false;
        for (int t = 0; t < 256 && !done; ++t) {
            uint32_t cafter = cum + part[t];
            bool cross = (cafter >= (uint32_t)MREF) ||
                         (pi < NPART && cafter >= (uint32_t)(pi * PQUOTA));
            if (cross) {
                int tp = NBUCK - 1 - t * 32;
                for (int k2 = 0; k2 < 32 && !done; ++k2) {
                    int b = tp - k2;
                    uint32_t prev = cum;
                    cum += h[b];
                    while (pi < NPART && cum >= (uint32_t)(pi * PQUOTA)) {
                        Bloc[pi] = b; Ploc[pi] = prev; ++pi;
                    }
                    if (cum >= (uint32_t)MREF) { H = b; T = cum; done = true; }
                }
            } else {
                cum = cafter;
            }
        }
        for (int p = pi; p < NPART; ++p) { Bloc[p] = H - 1; Ploc[p] = T; }
        if (T > (uint32_t)CAP) T = (uint32_t)CAP;
        Hrow[row] = (uint32_t)H;
        Bs[row * NPART + 0] = NBUCK; // sentinel, unused in membership test
        for (int p = 1; p < NPART; ++p) Bs[row * NPART + p] = Bloc[p];
        for (int p = 0; p < NPART; ++p) {
            uint32_t st = Ploc[p];
            if (st > (uint32_t)CAP) st = (uint32_t)CAP;
            pcur[row * NPART + p] = st;
            pse[row * (NPART + 1) + p] = st;
        }
        pse[row * (NPART + 1) + NPART] = T;
    }
}

// Round-3 k_compact structure; single-counter reservation replaced by
// per-partition LDS counts (k_hist-proven LDS atomics) + 8 global reserves.
__global__ void k_compact(const float* __restrict__ sc, const uint32_t* __restrict__ Hrow,
                          const int* __restrict__ Bs, uint32_t* __restrict__ pcur,
                          uint64_t* __restrict__ cand) {
    __shared__ int bsL[NPART];
    __shared__ uint32_t cnt8[NPART];
    __shared__ uint32_t base8[NPART];
    int row = blockIdx.x >> 7;
    int base = (blockIdx.x & 127) << 10;
    uint32_t H = Hrow[row];
    if (threadIdx.x < NPART) {
        bsL[threadIdx.x] = Bs[row * NPART + threadIdx.x];
        cnt8[threadIdx.x] = 0u;
    }
    __syncthreads();
    const float* p = sc + row * NCOLS + base;

    uint32_t myu[4], mycol[4], myr[4];
    int myp[4];
    uint32_t n = 0;
    for (int k = 0; k < 4; ++k) {
        int c = (int)threadIdx.x + (k << 8);
        uint32_t u = orderable(p[c]);
        uint32_t b = u >> USHIFT;
        if (b >= H) {
            int pp = 0;
            for (int q = 1; q < NPART; ++q) pp += ((int)b <= bsL[q]) ? 1 : 0;
            myu[n] = u; mycol[n] = (uint32_t)(base + c); myp[n] = pp;
            myr[n] = atomicAdd(&cnt8[pp], 1u);
            ++n;
        }
    }
    __syncthreads();
    if (threadIdx.x < NPART)
        base8[threadIdx.x] = atomicAdd(&pcur[row * NPART + threadIdx.x], cnt8[threadIdx.x]);
    __syncthreads();
    uint64_t* cr = cand + (size_t)row * CAP;
    for (uint32_t k = 0; k < n; ++k) {
        uint32_t idx = base8[myp[k]] + myr[k];
        if (idx < (uint32_t)CAP)
            cr[idx] = ((uint64_t)(~myu[k]) << 32) | mycol[k];
    }
}

// 32 blocks = 4 rows x 8 partitions, each bitonic-sorts its segment with a
// FIXED P=2048 network (round-3 k_sort structure, compile-time trip counts).
// Partitions are globally ordered by bucket, so each block writes its own
// slice of rv/ri at absolute positions start+i.
__global__ void k_psort(const uint32_t* __restrict__ pse, uint64_t* __restrict__ cand,
                        float* __restrict__ rv, uint32_t* __restrict__ ri) {
    __shared__ uint64_t lds[PARTCAP]; // 16 KiB
    int row = blockIdx.x >> 3;
    int pp  = blockIdx.x & 7;
    uint32_t start = pse[row * (NPART + 1) + pp];
    uint32_t end   = pse[row * (NPART + 1) + pp + 1];
    if (end > (uint32_t)CAP) end = (uint32_t)CAP;
    uint32_t n = (end > start) ? (end - start) : 0u;
    if (n > (uint32_t)PARTCAP) n = (uint32_t)PARTCAP;
    uint64_t* seg = cand + (size_t)row * CAP + start;
    for (uint32_t i = threadIdx.x; i < PARTCAP; i += blockDim.x)
        lds[i] = (i < n) ? seg[i] : ~0ULL;
    __syncthreads();
    for (uint32_t k = 2; k <= (uint32_t)PARTCAP; k <<= 1) {
        for (uint32_t j = k >> 1; j > 0; j >>= 1) {
            for (uint32_t i = threadIdx.x; i < (uint32_t)PARTCAP; i += blockDim.x) {
                uint32_t ixj = i ^ j;
                if (ixj > i) {
                    uint64_t a = lds[i], bb = lds[ixj];
                    bool up = ((i & k) == 0);
                    if ((a > bb) == up) { lds[i] = bb; lds[ixj] = a; }
                }
            }
            __syncthreads();
        }
    }
    for (uint32_t i = threadIdx.x; i < n; i += blockDim.x) {
        uint32_t gpos = start + i;
        if (gpos < (uint32_t)MREF) {
            uint64_t key = lds[i];
            uint32_t u = ~(uint32_t)(key >> 32);
            rv[row * MREF + gpos] = unorderable(u);
            ri[row * MREF + gpos] = (uint32_t)(key & 0xFFFFFFFFu);
        }
    }
}

// Round-3 exact: nearest-ref mapping with float32 tie emulation.
__global__ void k_map(const float* __restrict__ sc, const float* __restrict__ rv,
                      const uint32_t* __restrict__ ri, int* __restrict__ out) {
    __shared__ float srv[MREF]; // 16 KiB
    int row = blockIdx.x >> 9;
    int col = ((blockIdx.x & 511) << 8) + threadIdx.x;
    const float* rvr = rv + row * MREF;
    for (int t = threadIdx.x; t < MREF; t += blockDim.x) srv[t] = rvr[t];
    __syncthreads();

    float s = sc[row * NCOLS + col];
    // first j with srv[j] <= s (srv descending)
    int lo = 0, hi = MREF;
    while (lo < hi) { int mid = (lo + hi) >> 1; if (srv[mid] <= s) hi = mid; else lo = mid + 1; }
    int p = lo, jmin;
    if (p == 0) jmin = 0;
    else if (p == MREF) jmin = MREF - 1;
    else {
        float dp = fabsf(s - srv[p]);
        float dm = fabsf(s - srv[p - 1]);
        jmin = (dm <= dp) ? (p - 1) : p; // tie -> smaller j (argmax-first)
    }
    float pmax = -fabsf(s - srv[jmin]);
    int jans = jmin;
    // exp-level tie merge: exp(pw - pmax) rounds to 1.0f => equal softmax prob,
    // argmax picks the smallest such j; winner set is contiguous.
    for (int j = jmin - 1; j >= 0; --j) {
        float pw = -fabsf(s - srv[j]);
        if (expf(pw - pmax) == 1.0f) jans = j; else break;
    }
    out[row * NCOLS + col] = (int)ri[row * MREF + jans];
}

extern "C" void kernel_launch(void* const* d_in, const int* in_sizes, int n_in,
                              void* d_out, int out_size, void* d_ws, size_t ws_size,
                              hipStream_t stream) {
    const float* sc = (const float*)d_in[0];
    int* out = (int*)d_out;
    char* w = (char*)d_ws;

    // ws layout (bytes):
    //   hist [4*8192 u32] @ 0       (131072) <- k_zero
    //   Hrow [4 u32]      @ 131072  (pad 128)
    //   Bs   [4*8 int]    @ 131200  (128)
    //   pcur [4*8 u32]    @ 131328  (128)
    //   pse  [4*9 u32]    @ 131456  (pad 256)
    //   cand [4*6144 u64] @ 131712  (196608)
    //   rv   [4*4096 f32] @ 328320  (65536)
    //   ri   [4*4096 u32] @ 393856  (65536)  -> total 459392
    uint32_t* hist = (uint32_t*)w;
    uint32_t* Hrow = (uint32_t*)(w + 131072);
    int*      Bs   = (int*)     (w + 131200);
    uint32_t* pcur = (uint32_t*)(w + 131328);
    uint32_t* pse  = (uint32_t*)(w + 131456);
    uint64_t* cand = (uint64_t*)(w + 131712);
    float*    rv   = (float*)   (w + 328320);
    uint32_t* ri   = (uint32_t*)(w + 393856);

    k_zero   <<<64, 256, 0, stream>>>(hist);
    k_hist   <<<BROWS * HIST_BLK_PER_ROW, 256, 0, stream>>>(sc, hist);
    k_thresh <<<BROWS, 256, 0, stream>>>(hist, Hrow, Bs, pcur, pse);
    k_compact<<<512, 256, 0, stream>>>(sc, Hrow, Bs, pcur, cand);
    k_psort  <<<BROWS * NPART, 512, 0, stream>>>(pse, cand, rv, ri);
    k_map    <<<BROWS * 512, 256, 0, stream>>>(sc, rv, ri, out);
}

// Round 8
// 69.391 us; speedup vs baseline: 9.3951x; 1.2455x over previous
//
#include <hip/hip_runtime.h>
#include <stdint.h>

// Problem constants (fixed by reference: scores (4, 131072) f32, m=4096, tau=1)
#define BROWS 4
#define NCOLS 131072           // 2^17
#define MREF  4096
#define HIST_BITS 13
#define NBUCK (1 << HIST_BITS) // 8192
#define USHIFT (32 - HIST_BITS)
#define CAP 6144               // candidates per row (<= 4095 + threshold-bucket count)
#define HIST_BLK_PER_ROW 8
#define NPART 32
#define PQUOTA 192             // CAP / NPART
#define PARTCAP 1024           // fixed bitonic size; max partition = 192 + ~600 bucket

__device__ __forceinline__ uint32_t orderable(float f) {
    uint32_t u = __float_as_uint(f);
    return (u & 0x80000000u) ? ~u : (u | 0x80000000u);
}
__device__ __forceinline__ float unorderable(uint32_t u) {
    uint32_t b = (u & 0x80000000u) ? (u & 0x7FFFFFFFu) : ~u;
    return __uint_as_float(b);
}

__global__ void k_zero(uint32_t* hist) {
    int i = blockIdx.x * blockDim.x + threadIdx.x;
    int tot = BROWS * NBUCK;
    for (; i < tot; i += gridDim.x * blockDim.x) hist[i] = 0u;
}

// LDS-privatized histogram: 8 blocks/row over 16384-element chunks. (round-3 exact)
__global__ void k_hist(const float* __restrict__ sc, uint32_t* __restrict__ hist) {
    __shared__ uint32_t h[NBUCK]; // 32 KiB
    for (int t = threadIdx.x; t < NBUCK; t += blockDim.x) h[t] = 0u;
    __syncthreads();
    int row  = blockIdx.x / HIST_BLK_PER_ROW;
    int part = blockIdx.x % HIST_BLK_PER_ROW;
    const int CHUNK = NCOLS / HIST_BLK_PER_ROW; // 16384
    const float* p = sc + row * NCOLS + part * CHUNK;
    for (int c = threadIdx.x; c < CHUNK; c += blockDim.x) {
        uint32_t u = orderable(p[c]);
        atomicAdd(&h[u >> USHIFT], 1u);
    }
    __syncthreads();
    uint32_t* g = hist + (row << HIST_BITS);
    for (int t = threadIdx.x; t < NBUCK; t += blockDim.x) {
        uint32_t v = h[t];
        if (v) atomicAdd(&g[t], v);
    }
}

// One block per row: round-7-proven structure (part[] presums + thread-0 walk),
// now with NPART=32 quota boundaries.
__global__ void k_thresh(const uint32_t* __restrict__ hist, uint32_t* __restrict__ Hrow,
                         int* __restrict__ Bs, uint32_t* __restrict__ pcur,
                         uint32_t* __restrict__ pse) {
    __shared__ uint32_t part[256];
    int row = blockIdx.x;
    const uint32_t* h = hist + (row << HIST_BITS);
    int bhi = NBUCK - 1 - (int)threadIdx.x * 32;
    uint32_t run = 0;
    for (int k = 0; k < 32; ++k) run += h[bhi - k];
    part[threadIdx.x] = run;
    __syncthreads();
    if (threadIdx.x == 0) {
        int      Bloc[NPART];
        uint32_t Ploc[NPART];
        for (int p = 0; p < NPART; ++p) { Bloc[p] = -1; Ploc[p] = 0u; }
        uint32_t cum = 0, T = 0;
        int H = 0, pi = 1;
        bool done = false;
        for (int t = 0; t < 256 && !done; ++t) {
            uint32_t cafter = cum + part[t];
            bool cross = (cafter >= (uint32_t)MREF) ||
                         (pi < NPART && cafter >= (uint32_t)(pi * PQUOTA));
            if (cross) {
                int tp = NBUCK - 1 - t * 32;
                for (int k2 = 0; k2 < 32 && !done; ++k2) {
                    int b = tp - k2;
                    uint32_t prev = cum;
                    cum += h[b];
                    while (pi < NPART && cum >= (uint32_t)(pi * PQUOTA)) {
                        Bloc[pi] = b; Ploc[pi] = prev; ++pi;
                    }
                    if (cum >= (uint32_t)MREF) { H = b; T = cum; done = true; }
                }
            } else {
                cum = cafter;
            }
        }
        for (int p = pi; p < NPART; ++p) { Bloc[p] = H - 1; Ploc[p] = T; }
        if (T > (uint32_t)CAP) T = (uint32_t)CAP;
        Hrow[row] = (uint32_t)H;
        Bs[row * NPART + 0] = NBUCK; // sentinel, unused in membership test
        for (int p = 1; p < NPART; ++p) Bs[row * NPART + p] = Bloc[p];
        for (int p = 0; p < NPART; ++p) {
            uint32_t st = Ploc[p];
            if (st > (uint32_t)CAP) st = (uint32_t)CAP;
            pcur[row * NPART + p] = st;
            pse[row * (NPART + 1) + p] = st;
        }
        pse[row * (NPART + 1) + NPART] = T;
    }
}

// Round-7-proven structure; per-partition LDS counts + NPART global reserves.
__global__ void k_compact(const float* __restrict__ sc, const uint32_t* __restrict__ Hrow,
                          const int* __restrict__ Bs, uint32_t* __restrict__ pcur,
                          uint64_t* __restrict__ cand) {
    __shared__ int bsL[NPART];
    __shared__ uint32_t cntP[NPART];
    __shared__ uint32_t baseP[NPART];
    int row = blockIdx.x >> 7;
    int base = (blockIdx.x & 127) << 10;
    uint32_t H = Hrow[row];
    if (threadIdx.x < NPART) {
        bsL[threadIdx.x] = Bs[row * NPART + threadIdx.x];
        cntP[threadIdx.x] = 0u;
    }
    __syncthreads();
    const float* p = sc + row * NCOLS + base;

    uint32_t myu[4], mycol[4], myr[4];
    int myp[4];
    uint32_t n = 0;
    for (int k = 0; k < 4; ++k) {
        int c = (int)threadIdx.x + (k << 8);
        uint32_t u = orderable(p[c]);
        uint32_t b = u >> USHIFT;
        if (b >= H) {
            int pp = 0;
            for (int q = 1; q < NPART; ++q) pp += ((int)b <= bsL[q]) ? 1 : 0;
            myu[n] = u; mycol[n] = (uint32_t)(base + c); myp[n] = pp;
            myr[n] = atomicAdd(&cntP[pp], 1u);
            ++n;
        }
    }
    __syncthreads();
    if (threadIdx.x < NPART)
        baseP[threadIdx.x] = atomicAdd(&pcur[row * NPART + threadIdx.x], cntP[threadIdx.x]);
    __syncthreads();
    uint64_t* cr = cand + (size_t)row * CAP;
    for (uint32_t k = 0; k < n; ++k) {
        uint32_t idx = baseP[myp[k]] + myr[k];
        if (idx < (uint32_t)CAP)
            cr[idx] = ((uint64_t)(~myu[k]) << 32) | mycol[k];
    }
}

// 128 blocks = 4 rows x 32 partitions, each bitonic-sorts its segment with a
// FIXED P=1024 network (55 phases, 2 sweeps each at 512 threads). Partitions
// are globally ordered by bucket -> each block writes its slice of rv/ri.
__global__ void k_psort(const uint32_t* __restrict__ pse, uint64_t* __restrict__ cand,
                        float* __restrict__ rv, uint32_t* __restrict__ ri) {
    __shared__ uint64_t lds[PARTCAP]; // 8 KiB
    int row = blockIdx.x >> 5;
    int pp  = blockIdx.x & 31;
    uint32_t start = pse[row * (NPART + 1) + pp];
    uint32_t end   = pse[row * (NPART + 1) + pp + 1];
    if (end > (uint32_t)CAP) end = (uint32_t)CAP;
    uint32_t n = (end > start) ? (end - start) : 0u;
    if (n > (uint32_t)PARTCAP) n = (uint32_t)PARTCAP;
    uint64_t* seg = cand + (size_t)row * CAP + start;
    for (uint32_t i = threadIdx.x; i < (uint32_t)PARTCAP; i += blockDim.x)
        lds[i] = (i < n) ? seg[i] : ~0ULL;
    __syncthreads();
    for (uint32_t k = 2; k <= (uint32_t)PARTCAP; k <<= 1) {
        for (uint32_t j = k >> 1; j > 0; j >>= 1) {
            for (uint32_t i = threadIdx.x; i < (uint32_t)PARTCAP; i += blockDim.x) {
                uint32_t ixj = i ^ j;
                if (ixj > i) {
                    uint64_t a = lds[i], bb = lds[ixj];
                    bool up = ((i & k) == 0);
                    if ((a > bb) == up) { lds[i] = bb; lds[ixj] = a; }
                }
            }
            __syncthreads();
        }
    }
    for (uint32_t i = threadIdx.x; i < n; i += blockDim.x) {
        uint32_t gpos = start + i;
        if (gpos < (uint32_t)MREF) {
            uint64_t key = lds[i];
            uint32_t u = ~(uint32_t)(key >> 32);
            rv[row * MREF + gpos] = unorderable(u);
            ri[row * MREF + gpos] = (uint32_t)(key & 0xFFFFFFFFu);
        }
    }
}

// Round-3 exact: nearest-ref mapping with float32 tie emulation.
__global__ void k_map(const float* __restrict__ sc, const float* __restrict__ rv,
                      const uint32_t* __restrict__ ri, int* __restrict__ out) {
    __shared__ float srv[MREF]; // 16 KiB
    int row = blockIdx.x >> 9;
    int col = ((blockIdx.x & 511) << 8) + threadIdx.x;
    const float* rvr = rv + row * MREF;
    for (int t = threadIdx.x; t < MREF; t += blockDim.x) srv[t] = rvr[t];
    __syncthreads();

    float s = sc[row * NCOLS + col];
    // first j with srv[j] <= s (srv descending)
    int lo = 0, hi = MREF;
    while (lo < hi) { int mid = (lo + hi) >> 1; if (srv[mid] <= s) hi = mid; else lo = mid + 1; }
    int p = lo, jmin;
    if (p == 0) jmin = 0;
    else if (p == MREF) jmin = MREF - 1;
    else {
        float dp = fabsf(s - srv[p]);
        float dm = fabsf(s - srv[p - 1]);
        jmin = (dm <= dp) ? (p - 1) : p; // tie -> smaller j (argmax-first)
    }
    float pmax = -fabsf(s - srv[jmin]);
    int jans = jmin;
    // exp-level tie merge: exp(pw - pmax) rounds to 1.0f => equal softmax prob,
    // argmax picks the smallest such j; winner set is contiguous.
    for (int j = jmin - 1; j >= 0; --j) {
        float pw = -fabsf(s - srv[j]);
        if (expf(pw - pmax) == 1.0f) jans = j; else break;
    }
    out[row * NCOLS + col] = (int)ri[row * MREF + jans];
}

extern "C" void kernel_launch(void* const* d_in, const int* in_sizes, int n_in,
                              void* d_out, int out_size, void* d_ws, size_t ws_size,
                              hipStream_t stream) {
    const float* sc = (const float*)d_in[0];
    int* out = (int*)d_out;
    char* w = (char*)d_ws;

    // ws layout (bytes):
    //   hist [4*8192 u32] @ 0       (131072) <- k_zero
    //   Hrow [4 u32]      @ 131072  (pad 128)
    //   Bs   [4*32 int]   @ 131200  (512)
    //   pcur [4*32 u32]   @ 131712  (512)
    //   pse  [4*33 u32]   @ 132224  (528, pad 640)
    //   cand [4*6144 u64] @ 132864  (196608)
    //   rv   [4*4096 f32] @ 329472  (65536)
    //   ri   [4*4096 u32] @ 395008  (65536)  -> total 460544
    uint32_t* hist = (uint32_t*)w;
    uint32_t* Hrow = (uint32_t*)(w + 131072);
    int*      Bs   = (int*)     (w + 131200);
    uint32_t* pcur = (uint32_t*)(w + 131712);
    uint32_t* pse  = (uint32_t*)(w + 132224);
    uint64_t* cand = (uint64_t*)(w + 132864);
    float*    rv   = (float*)   (w + 329472);
    uint32_t* ri   = (uint32_t*)(w + 395008);

    k_zero   <<<64, 256, 0, stream>>>(hist);
    k_hist   <<<BROWS * HIST_BLK_PER_ROW, 256, 0, stream>>>(sc, hist);
    k_thresh <<<BROWS, 256, 0, stream>>>(hist, Hrow, Bs, pcur, pse);
    k_compact<<<512, 256, 0, stream>>>(sc, Hrow, Bs, pcur, cand);
    k_psort  <<<BROWS * NPART, 512, 0, stream>>>(pse, cand, rv, ri);
    k_map    <<<BROWS * 512, 256, 0, stream>>>(sc, rv, ri, out);
}